// Round 4
// baseline (104.064 us; speedup 1.0000x reference)
//
#include <hip/hip_runtime.h>

// Segment-sum via on-device bucketing (scatter->gather inversion).
//   ws layout: [ cnt: N int ][ bucket: N*CAP int ]
// CAP=64 slots/node; avg load 16 (Poisson) -> overflow prob ~1e-14, but a
// correct atomic fallback handles slot>=CAP anyway.
//
// Gather v3: 4 lane-groups, 16 rows per iteration -> 4 independent float4
// load instructions (4KB) in flight per wave before any waitcnt. Avg node
// (c=16) completes in ONE dependent HBM round: (cnt || bucket) -> 4x H.
#define CAP 64

// ---- fallback: direct atomic scatter (used only if ws_size too small) ----
__global__ void AggrSum_scatter(const float* __restrict__ H,
                                const int* __restrict__ idx,
                                float* __restrict__ out,
                                int E) {
    const int t = blockIdx.x * blockDim.x + threadIdx.x;
    const int quads = E * 16;
    if (t >= quads) return;
    const int e = t >> 4;
    const int q = t & 15;
    const int node = idx[e];
    const float4 v = reinterpret_cast<const float4*>(H)[(size_t)t];
    float* o = out + (size_t)node * 64 + (size_t)q * 4;
    atomicAdd(o + 0, v.x);
    atomicAdd(o + 1, v.y);
    atomicAdd(o + 2, v.z);
    atomicAdd(o + 3, v.w);
}

// ---- pass 1: bucket fill. One int atomic per edge. ----
__global__ void AggrSum_fill(const int* __restrict__ idx,
                             const float* __restrict__ H,
                             int* __restrict__ cnt,
                             int* __restrict__ bucket,
                             float* __restrict__ out,
                             int E) {
    const int e = blockIdx.x * blockDim.x + threadIdx.x;
    if (e >= E) return;
    const int n = idx[e];
    const int slot = atomicAdd(&cnt[n], 1);
    if (slot < CAP) {
        bucket[(size_t)n * CAP + slot] = e;
    } else {
        // overflow (practically never): add this row directly into out
        const float* h = H + (size_t)e * 64;
        float* o = out + (size_t)n * 64;
        for (int d = 0; d < 64; ++d) atomicAdd(o + d, h[d]);
    }
}

// ---- pass 2: per-node gather, 4 loads in flight per wave. ----
// lane = (g, q): g = lane>>4 (edge sub-group), q = lane&15 (float4 slot).
// Iteration i: group g loads rows of bucket entries i+g, i+4+g, i+8+g,
// i+12+g as float4 (4 independent load instrs). Cross-group reduce via
// shfl_xor(16,32); lanes 0..15 store one float4 each.
__global__ void AggrSum_gather(const float* __restrict__ H,
                               const int* __restrict__ cnt,
                               const int* __restrict__ bucket,
                               float* __restrict__ out,
                               int N) {
    const int lane = threadIdx.x & 63;
    const int wv   = threadIdx.x >> 6;
    const int n    = blockIdx.x * 4 + wv;       // 256 threads = 4 waves/block
    if (n >= N) return;
    const int c  = cnt[n];
    const int cc = c < CAP ? c : CAP;
    // lane i holds bucket entry i (one coalesced 256B read per wave)
    const int myid = bucket[(size_t)n * CAP + lane];
    const int g = lane >> 4;
    const int q = lane & 15;

    float4 a0 = make_float4(0.f, 0.f, 0.f, 0.f);
    float4 a1 = make_float4(0.f, 0.f, 0.f, 0.f);
    float4 a2 = make_float4(0.f, 0.f, 0.f, 0.f);
    float4 a3 = make_float4(0.f, 0.f, 0.f, 0.f);
    for (int i = 0; i < cc; i += 16) {
        const int j0 = i + g;
        const int j1 = i + 4 + g;
        const int j2 = i + 8 + g;
        const int j3 = i + 12 + g;
        const int e0 = __shfl(myid, j0);
        const int e1 = __shfl(myid, j1);
        const int e2 = __shfl(myid, j2);
        const int e3 = __shfl(myid, j3);
        // predicated: bucket slots >= cc hold garbage (poisoned ws)
        if (j0 < cc) {
            const float4 v = reinterpret_cast<const float4*>(H + (size_t)e0 * 64)[q];
            a0.x += v.x; a0.y += v.y; a0.z += v.z; a0.w += v.w;
        }
        if (j1 < cc) {
            const float4 v = reinterpret_cast<const float4*>(H + (size_t)e1 * 64)[q];
            a1.x += v.x; a1.y += v.y; a1.z += v.z; a1.w += v.w;
        }
        if (j2 < cc) {
            const float4 v = reinterpret_cast<const float4*>(H + (size_t)e2 * 64)[q];
            a2.x += v.x; a2.y += v.y; a2.z += v.z; a2.w += v.w;
        }
        if (j3 < cc) {
            const float4 v = reinterpret_cast<const float4*>(H + (size_t)e3 * 64)[q];
            a3.x += v.x; a3.y += v.y; a3.z += v.z; a3.w += v.w;
        }
    }

    float4 acc;
    acc.x = (a0.x + a1.x) + (a2.x + a3.x);
    acc.y = (a0.y + a1.y) + (a2.y + a3.y);
    acc.z = (a0.z + a1.z) + (a2.z + a3.z);
    acc.w = (a0.w + a1.w) + (a2.w + a3.w);

    // reduce the 4 groups (lanes l, l^16, l^32, l^48 hold partials of slot q)
    acc.x += __shfl_xor(acc.x, 16); acc.y += __shfl_xor(acc.y, 16);
    acc.z += __shfl_xor(acc.z, 16); acc.w += __shfl_xor(acc.w, 16);
    acc.x += __shfl_xor(acc.x, 32); acc.y += __shfl_xor(acc.y, 32);
    acc.z += __shfl_xor(acc.z, 32); acc.w += __shfl_xor(acc.w, 32);

    if (g == 0) {
        float4* o = reinterpret_cast<float4*>(out + (size_t)n * 64) + q;
        if (c > CAP) {                          // merge overflow contributions
            float4 prev = *o;
            acc.x += prev.x; acc.y += prev.y; acc.z += prev.z; acc.w += prev.w;
        }
        *o = acc;
    }
}

extern "C" void kernel_launch(void* const* d_in, const int* in_sizes, int n_in,
                              void* d_out, int out_size, void* d_ws, size_t ws_size,
                              hipStream_t stream) {
    const float* H   = (const float*)d_in[0];
    const int*   idx = (const int*)d_in[1];
    float*       out = (float*)d_out;
    const int E = in_sizes[1];                  // 800000
    const int D = in_sizes[0] / E;              // 64
    const int N = out_size / D;                 // 50000

    const size_t need = (size_t)N * sizeof(int) + (size_t)N * CAP * sizeof(int);

    if (ws_size < need) {
        // fallback: atomic scatter
        hipMemsetAsync(d_out, 0, (size_t)out_size * sizeof(float), stream);
        const int quads = E * 16;
        AggrSum_scatter<<<(quads + 255) / 256, 256, 0, stream>>>(H, idx, out, E);
        return;
    }

    int* cnt    = (int*)d_ws;
    int* bucket = cnt + N;

    // zero cnt every call; zero out for the (never-taken) overflow-atomic path
    hipMemsetAsync(cnt, 0, (size_t)N * sizeof(int), stream);
    hipMemsetAsync(d_out, 0, (size_t)out_size * sizeof(float), stream);

    AggrSum_fill<<<(E + 255) / 256, 256, 0, stream>>>(idx, H, cnt, bucket, out, E);

    const int nodes_per_block = 4;              // 256 threads = 4 waves
    AggrSum_gather<<<(N + nodes_per_block - 1) / nodes_per_block, 256, 0, stream>>>(
        H, cnt, bucket, out, N);
}